// Round 7
// baseline (5257.151 us; speedup 1.0000x reference)
//
#include <hip/hip_runtime.h>

#define FHH 38
#define FWW 63
#define NPIX 2394        // 38*63
#define BATCH 8
#define CIN 1024
#define CMID 512
#define NSC 21546        // NPIX*9
#define M_TOT 19152      // BATCH*NPIX
#define K_TOT 9216       // CIN*9
#define PRE_N 2000
#define POST_N 300

typedef double f64x4 __attribute__((ext_vector_type(4)));

// exact anchors (generate_anchors(16,(0.5,1,2),(8,16,32))) — integer-valued, exact in any fp
__device__ const double ANCX1[9] = {-84.,-176.,-360.,-56.,-120.,-248.,-36.,-80.,-168.};
__device__ const double ANCY1[9] = {-40.,-88.,-184.,-56.,-120.,-248.,-80.,-168.,-344.};
__device__ const double ANCX2[9] = {99.,191.,375.,71.,135.,263.,51.,95.,183.};
__device__ const double ANCY2[9] = {55.,103.,199.,71.,135.,263.,95.,183.,359.};

// ---------------------------------------------------------------------------
// Probe: derives the TRUE lane mapping of v_mfma_f64_16x16x4f64 (1 wave).
// tab[0..63] a_row | [64..127] a_k | [128..191] b_k | [192..255] b_col
// [256..511] d_row[l*4+r] | [512..767] d_col[l*4+r]
// ---------------------------------------------------------------------------
__global__ void mfma_probe_kernel(int* __restrict__ tab) {
    const int l = threadIdx.x;   // 64 lanes
    __shared__ int aiS[64], bjS[64], kbS[64];
    const f64x4 zero = {0.0, 0.0, 0.0, 0.0};
    int di[4] = {-1, -1, -1, -1}, dj[4] = {-1, -1, -1, -1};
    int ai_l = 0, bj_l = 0, ka_l = 0;
    kbS[l] = 0x7fffffff;
    __syncthreads();

    const double bval = __longlong_as_double((long long)(1023 + l) << 52);  // 2^l exact
    for (int p = 0; p < 64; ++p) {
        double a = (l == p) ? 1.0 : 0.0;
        f64x4 d = __builtin_amdgcn_mfma_f64_16x16x4f64(a, bval, zero, 0, 0, 0);
        int lmin = 0x7fffffff, kmin = 0x7fffffff;
        bool lit[4]; int qv[4];
#pragma unroll
        for (int r = 0; r < 4; ++r) {
            lit[r] = (d[r] != 0.0);
            qv[r] = ((__double2hiint(d[r]) >> 20) & 0x7ff) - 1023;
            if (lit[r]) {
                lmin = min(lmin, di[r] < 0 ? p : di[r]);
                kmin = min(kmin, qv[r]);
            }
        }
#pragma unroll
        for (int off = 32; off > 0; off >>= 1) {
            lmin = min(lmin, __shfl_xor(lmin, off));
            kmin = min(kmin, __shfl_xor(kmin, off));
        }
#pragma unroll
        for (int r = 0; r < 4; ++r)
            if (lit[r]) { di[r] = lmin; atomicMin(&kbS[qv[r]], kmin); }
        if (l == p) { ai_l = lmin; ka_l = kmin; }
    }
    for (int q = 0; q < 64; ++q) {
        double b = (l == q) ? 1.0 : 0.0;
        f64x4 d = __builtin_amdgcn_mfma_f64_16x16x4f64(1.0, b, zero, 0, 0, 0);
        int lmin = 0x7fffffff;
        bool lit[4];
#pragma unroll
        for (int r = 0; r < 4; ++r) {
            lit[r] = (d[r] != 0.0);
            if (lit[r]) lmin = min(lmin, dj[r] < 0 ? q : dj[r]);
        }
#pragma unroll
        for (int off = 32; off > 0; off >>= 1) lmin = min(lmin, __shfl_xor(lmin, off));
#pragma unroll
        for (int r = 0; r < 4; ++r) if (lit[r]) dj[r] = lmin;
        if (l == q) bj_l = lmin;
    }
    aiS[l] = ai_l; bjS[l] = bj_l;
    __syncthreads();
    int kb_l = kbS[l];
    int a_row_rk = 0, a_k_rk = 0, b_k_rk = 0, b_col_rk = 0;
    for (int t = 0; t < 64; ++t) {
        a_row_rk += (aiS[t] == t && t < ai_l);
        b_col_rk += (bjS[t] == t && t < bj_l);
        a_k_rk   += (kbS[t] == t && t < ka_l);
        b_k_rk   += (kbS[t] == t && t < kb_l);
    }
    tab[l] = a_row_rk; tab[64 + l] = a_k_rk; tab[128 + l] = b_k_rk; tab[192 + l] = b_col_rk;
#pragma unroll
    for (int r = 0; r < 4; ++r) {
        int dr = 0, dc = 0;
        for (int t = 0; t < 64; ++t) {
            dr += (aiS[t] == t && t < di[r]);
            dc += (bjS[t] == t && t < dj[r]);
        }
        tab[256 + l * 4 + r] = dr;
        tab[512 + l * 4 + r] = dc;
    }
}

// K0: W_conv [512][1024][3][3] -> Wt[k][co], k=(kh*3+kw)*1024+ci   (fp32, exact copy)
__global__ void wt3x3_kernel(const float* __restrict__ W, float* __restrict__ Wt) {
    int gid = blockIdx.x * 256 + threadIdx.x;
    if (gid >= K_TOT * CMID) return;
    int co = gid & 511;
    int k  = gid >> 9;
    int pl = k >> 10;        // kh*3+kw
    int ci = k & 1023;
    Wt[gid] = W[((size_t)co * CIN + ci) * 9 + pl];
}

// K0b: W_cls[18][512], W_bbox[36][512] -> Wt2pD[k][64] double
__global__ void wt1x1_kernel(const float* __restrict__ Wc, const float* __restrict__ Wb,
                             double* __restrict__ Wt2pD) {
    int gid = blockIdx.x * 256 + threadIdx.x;
    if (gid >= CMID * 64) return;
    int n = gid & 63, k = gid >> 6;
    double v = 0.0;
    if (n < 18)      v = (double)Wc[(size_t)n * CMID + k];
    else if (n < 54) v = (double)Wb[(size_t)(n - 18) * CMID + k];
    Wt2pD[gid] = v;
}

// K1: heterogeneous dual-pipe implicit-GEMM 3x3 conv + bias + relu.
//  blocks x<5: probed f64-MFMA path, cols [64*x, 64*x+64)   (matrix pipe)
//  blocks x>=5: fp64 VALU path, tile 64x96, cols [320+96*(x-5), ...)  (VALU pipe)
// Both: exact fp32 staging, fp64 accumulate. LDS = 40KB union -> 4 blocks/CU.
#define ASZ (32 * 72)
__global__ __launch_bounds__(256, 4) void conv3x3_fused(
    const float* __restrict__ x, const float* __restrict__ Wt,
    const float* __restrict__ bconv, const int* __restrict__ tab,
    double* __restrict__ feat) {
    __shared__ double u[5120];   // 40960 B union
    const int tid = threadIdx.x;
    const int m0 = blockIdx.y * 64;

    // common A-row mapping (verified since R2)
    const int mm = tid & 63;
    const int t6 = tid >> 6;          // 0..3
    const int m = m0 + mm;
    const bool vm = (m < M_TOT);
    int b = 0, yy = 0, xx = 0;
    if (vm) { b = m / NPIX; int r = m - b * NPIX; yy = r / FWW; xx = r - yy * FWW; }

    if (blockIdx.x < 5) {
        // ================= MFMA path (cols 0..319) =================
        float* Asf = (float*)u;            // 2 bufs * ASZ floats
        float* Bsf = (float*)u + 2 * ASZ;
        const int lane = tid & 63;
        const int wave = tid >> 6;
        const int wm = wave >> 1;
        const int wn = wave & 1;
        const int n0 = blockIdx.x * 64;

        const int aRow = tab[lane];
        const int aK   = tab[64 + lane];
        const int bK   = tab[128 + lane];
        const int bCol = tab[192 + lane];
        int dRow[4], dCol[4];
#pragma unroll
        for (int r = 0; r < 4; ++r) {
            dRow[r] = tab[256 + lane * 4 + r];
            dCol[r] = tab[512 + lane * 4 + r];
        }
        const int bk2 = tid >> 4;         // 0..15
        const int bn2 = (tid & 15) << 2;  // 0..60

        f64x4 acc[2][2];
#pragma unroll
        for (int i = 0; i < 2; ++i)
#pragma unroll
            for (int j = 0; j < 2; ++j) acc[i][j] = (f64x4){0.0, 0.0, 0.0, 0.0};

        const float* aBase = Asf + aK * 72 + wm * 32 + aRow;
        const float* bBase = Bsf + bK * 72 + wn * 32 + bCol;

#define STAGE_REGS(KC, VA, VB0, VB1) do {                                     \
        const int pl_ = (KC) >> 5;                                            \
        const int kh_ = pl_ / 3, kw_ = pl_ - kh_ * 3;                         \
        const int ci0_ = ((KC) & 31) << 5;                                    \
        const int iy_ = yy + kh_ - 1, ix_ = xx + kw_ - 1;                     \
        const bool ok_ = vm && (iy_ >= 0) && (iy_ < FHH) && (ix_ >= 0) && (ix_ < FWW); \
        const float* ap_ = x + ((size_t)(b * CIN + ci0_ + t6)) * NPIX + iy_ * FWW + ix_; \
        _Pragma("unroll")                                                     \
        for (int r = 0; r < 8; ++r) {                                         \
            float v_ = 0.f;                                                   \
            if (ok_) v_ = ap_[(size_t)r * 4 * NPIX];                          \
            VA[r] = v_;                                                       \
        }                                                                     \
        const float4* wp_ = (const float4*)(Wt + (size_t)(((KC) << 5) + bk2) * CMID + n0 + bn2); \
        VB0 = wp_[0];                                                         \
        VB1 = wp_[2048];                                                      \
    } while (0)

#define WRITE_TILE(BUF, VA, VB0, VB1) do {                                    \
        _Pragma("unroll")                                                     \
        for (int r = 0; r < 8; ++r)                                           \
            Asf[(BUF) * ASZ + (t6 + r * 4) * 72 + mm] = VA[r];                \
        *(float4*)&Bsf[(BUF) * ASZ + bk2 * 72 + bn2] = VB0;                   \
        *(float4*)&Bsf[(BUF) * ASZ + (bk2 + 16) * 72 + bn2] = VB1;            \
    } while (0)

#define MFMA_PHASE(BUF) do {                                                  \
        _Pragma("unroll")                                                     \
        for (int ks = 0; ks < 8; ++ks) {                                      \
            double a0 = (double)aBase[(BUF) * ASZ + ks * 288];                \
            double a1 = (double)aBase[(BUF) * ASZ + ks * 288 + 16];           \
            double b0 = (double)bBase[(BUF) * ASZ + ks * 288];                \
            double b1 = (double)bBase[(BUF) * ASZ + ks * 288 + 16];           \
            acc[0][0] = __builtin_amdgcn_mfma_f64_16x16x4f64(a0, b0, acc[0][0], 0, 0, 0); \
            acc[0][1] = __builtin_amdgcn_mfma_f64_16x16x4f64(a0, b1, acc[0][1], 0, 0, 0); \
            acc[1][0] = __builtin_amdgcn_mfma_f64_16x16x4f64(a1, b0, acc[1][0], 0, 0, 0); \
            acc[1][1] = __builtin_amdgcn_mfma_f64_16x16x4f64(a1, b1, acc[1][1], 0, 0, 0); \
        }                                                                     \
    } while (0)

        float va[8]; float4 vb0, vb1;
        float wa[8]; float4 wb0, wb1;
        STAGE_REGS(0, va, vb0, vb1);
        WRITE_TILE(0, va, vb0, vb1);
        __syncthreads();

        for (int kc = 0; kc < 288; kc += 2) {
            STAGE_REGS(kc + 1, wa, wb0, wb1);
            MFMA_PHASE(0);
            WRITE_TILE(1, wa, wb0, wb1);
            __syncthreads();
            if (kc + 2 < 288) {
                STAGE_REGS(kc + 2, va, vb0, vb1);
                MFMA_PHASE(1);
                WRITE_TILE(0, va, vb0, vb1);
                __syncthreads();
            } else {
                MFMA_PHASE(1);
            }
        }
#undef STAGE_REGS
#undef WRITE_TILE
#undef MFMA_PHASE

#pragma unroll
        for (int mi = 0; mi < 2; ++mi) {
#pragma unroll
            for (int nj = 0; nj < 2; ++nj) {
#pragma unroll
                for (int r = 0; r < 4; ++r) {
                    int mg  = m0 + wm * 32 + mi * 16 + dRow[r];
                    int col = n0 + wn * 32 + nj * 16 + dCol[r];
                    if (mg < M_TOT)
                        feat[(size_t)mg * CMID + col] =
                            fmax(acc[mi][nj][r] + (double)bconv[col], 0.0);
                }
            }
        }
    } else {
        // ================= VALU path (cols 320..511, tile 64x96) =================
        double* Av = u;                 // [32][64] fp64, 16 KB
        double* Bv = u + 32 * 64;       // [32][96] fp64, 24 KB
        const int n0 = 320 + (blockIdx.x - 5) * 96;
        const int bk3 = tid >> 3;            // 0..31 (k-row)
        const int bc3 = (tid & 7) * 12;      // 0..84 (col base, 12 cols)
        const int tm = tid & 15;             // 4 rows each
        const int tn = tid >> 4;             // 6 cols each

        double acc[4][6];
#pragma unroll
        for (int i = 0; i < 4; ++i)
#pragma unroll
            for (int j = 0; j < 6; ++j) acc[i][j] = 0.0;

        for (int kc = 0; kc < 288; ++kc) {
            const int pl = kc >> 5;
            const int kh = pl / 3, kw = pl - kh * 3;
            const int ci0 = (kc & 31) << 5;
            const int iy = yy + kh - 1, ix = xx + kw - 1;
            const bool ok = vm && (iy >= 0) && (iy < FHH) && (ix >= 0) && (ix < FWW);
            const float* ap = x + ((size_t)(b * CIN + ci0 + t6)) * NPIX + iy * FWW + ix;
#pragma unroll
            for (int r = 0; r < 8; ++r) {
                float v = ok ? ap[(size_t)r * 4 * NPIX] : 0.f;
                Av[(t6 + r * 4) * 64 + mm] = (double)v;
            }
            const float* wrow = Wt + (size_t)((kc << 5) + bk3) * CMID + n0 + bc3;
            float4 w0 = *(const float4*)wrow;
            float4 w1 = *(const float4*)(wrow + 4);
            float4 w2 = *(const float4*)(wrow + 8);
            double* bd = &Bv[bk3 * 96 + bc3];
            bd[0] = (double)w0.x; bd[1]  = (double)w0.y; bd[2]  = (double)w0.z; bd[3]  = (double)w0.w;
            bd[4] = (double)w1.x; bd[5]  = (double)w1.y; bd[6]  = (double)w1.z; bd[7]  = (double)w1.w;
            bd[8] = (double)w2.x; bd[9]  = (double)w2.y; bd[10] = (double)w2.z; bd[11] = (double)w2.w;
            __syncthreads();
#pragma unroll 4
            for (int kk = 0; kk < 32; ++kk) {
                const double* ar = &Av[kk * 64 + tm * 4];
                const double* br = &Bv[kk * 96 + tn * 6];
                double a4[4] = {ar[0], ar[1], ar[2], ar[3]};
                double b6[6] = {br[0], br[1], br[2], br[3], br[4], br[5]};
#pragma unroll
                for (int i = 0; i < 4; ++i)
#pragma unroll
                    for (int j = 0; j < 6; ++j)
                        acc[i][j] = fma(a4[i], b6[j], acc[i][j]);
            }
            __syncthreads();
        }
#pragma unroll
        for (int i = 0; i < 4; ++i) {
            int mg = m0 + tm * 4 + i;
            if (mg < M_TOT) {
                double* dst = feat + (size_t)mg * CMID + n0 + tn * 6;
#pragma unroll
                for (int j = 0; j < 6; ++j)
                    dst[j] = fmax(acc[i][j] + (double)bconv[n0 + tn * 6 + j], 0.0);
            }
        }
    }
}

// K2: 1x1 convs (cls 18 + bbox 36 as 54 outputs), fp64. featD NHWC -> out54D[m][64]
__global__ __launch_bounds__(256) void conv1x1_kernel(
    const double* __restrict__ feat, const double* __restrict__ Wt2pD,
    const float* __restrict__ bcls, const float* __restrict__ bbx,
    double* __restrict__ out54) {
    __shared__ double As[4 * 512];
    __shared__ double Bsh[64 * 64];
    int tid = threadIdx.x;
    int m0 = blockIdx.x * 4;
    for (int off = tid; off < 2048; off += 256) As[off] = feat[(size_t)m0 * CMID + off];
    int p = tid >> 6, n = tid & 63;
    double acc = 0.0;
    for (int c = 0; c < 8; ++c) {
        __syncthreads();
        for (int off = tid; off < 4096; off += 256) Bsh[off] = Wt2pD[c * 4096 + off];
        __syncthreads();
        const double* ap = &As[p * 512 + c * 64];
#pragma unroll 8
        for (int k2 = 0; k2 < 64; ++k2) acc = fma(ap[k2], Bsh[k2 * 64 + n], acc);
    }
    if (n < 54) {
        double bias = (double)((n < 18) ? bcls[n] : bbx[n - 18]);
        out54[(size_t)(m0 + p) * 64 + n] = acc + bias;
    }
}

// K2b: softmax-pair score + bbox_transform_inv + clip, all fp64
__global__ void proposals_kernel(const double* __restrict__ out54, const float* __restrict__ iminfo,
                                 double* __restrict__ scoresD, double* __restrict__ propsD) {
    int gid = blockIdx.x * 256 + threadIdx.x;
    if (gid >= BATCH * NSC) return;
    int b = gid / NSC;
    int rem = gid - b * NSC;
    int p = rem / 9;
    int a = rem - p * 9;
    int y = p / FWW, x = p - y * FWW;
    int m = b * NPIX + p;
    const double* row = out54 + (size_t)m * 64;
    double s0 = row[a], s1 = row[9 + a];
    double mx = fmax(s0, s1);
    double e0 = exp(s0 - mx), e1 = exp(s1 - mx);
    scoresD[gid] = e1 / (e0 + e1);
    double dx = row[18 + 4 * a], dy = row[19 + 4 * a], dw = row[20 + 4 * a], dh = row[21 + 4 * a];
    double ax1 = x * 16.0 + ANCX1[a], ay1 = y * 16.0 + ANCY1[a];
    double ax2 = x * 16.0 + ANCX2[a], ay2 = y * 16.0 + ANCY2[a];
    double w = ax2 - ax1 + 1.0, h = ay2 - ay1 + 1.0;
    double cx = ax1 + 0.5 * w, cy = ay1 + 0.5 * h;
    double px = dx * w + cx, py = dy * h + cy;
    double pw = exp(dw) * w, ph = exp(dh) * h;
    double imh = (double)iminfo[b * 3 + 0], imw = (double)iminfo[b * 3 + 1];
    double x1 = fmin(fmax(px - 0.5 * pw, 0.0), imw - 1.0);
    double y1 = fmin(fmax(py - 0.5 * ph, 0.0), imh - 1.0);
    double x2 = fmin(fmax(px + 0.5 * pw, 0.0), imw - 1.0);
    double y2 = fmin(fmax(py + 0.5 * ph, 0.0), imh - 1.0);
    double* o = propsD + (size_t)gid * 4;
    o[0] = x1; o[1] = y1; o[2] = x2; o[3] = y2;
}

// K3: exact top-2000, stable lower-index ties. key = (double_score_bits & ~0x7FFF) | (~i & 0x7FFF)
__global__ __launch_bounds__(256) void select_kernel(const double* __restrict__ scoresD,
                                                     const double* __restrict__ propsD,
                                                     double* __restrict__ boxesD) {
    __shared__ unsigned int hist4[4][256];
    __shared__ unsigned int histf[256];
    __shared__ unsigned long long keys[2048];
    __shared__ unsigned long long sh_thr;
    __shared__ int sh_need;
    __shared__ int cnt;
    const int b = blockIdx.x, tid = threadIdx.x;
    const int w4 = tid >> 6;
    const double* sc = scoresD + (size_t)b * NSC;

    unsigned long long prefix = 0ull;
    int need = PRE_N;
    for (int d = 7; d >= 0; --d) {
        for (int z = tid; z < 1024; z += 256) ((unsigned int*)hist4)[z] = 0u;
        __syncthreads();
        const int shift = d * 8;
        const unsigned long long maskAbove = (d == 7) ? 0ull : (~0ull << (shift + 8));
        for (int i = tid; i < NSC; i += 256) {
            unsigned long long sb = (unsigned long long)__double_as_longlong(sc[i]);
            unsigned long long key = (sb & ~0x7FFFull) | (unsigned long long)((~i) & 0x7FFF);
            if (((key ^ prefix) & maskAbove) == 0ull)
                atomicAdd(&hist4[w4][(unsigned int)(key >> shift) & 255u], 1u);
        }
        __syncthreads();
        histf[tid] = hist4[0][tid] + hist4[1][tid] + hist4[2][tid] + hist4[3][tid];
        __syncthreads();
        if (tid == 0) {
            int acc = 0, v = 255;
            for (; v > 0; --v) {
                int c = (int)histf[v];
                if (acc + c >= need) break;
                acc += c;
            }
            sh_thr = prefix | ((unsigned long long)(unsigned int)v << shift);
            sh_need = need - acc;
        }
        __syncthreads();
        prefix = sh_thr;
        need = sh_need;
        __syncthreads();
    }
    if (tid == 0) cnt = 0;
    __syncthreads();
    for (int i = tid; i < NSC; i += 256) {
        unsigned long long sb = (unsigned long long)__double_as_longlong(sc[i]);
        unsigned long long key = (sb & ~0x7FFFull) | (unsigned long long)((~i) & 0x7FFF);
        if (key >= prefix) {
            int slot = atomicAdd(&cnt, 1);
            if (slot < 2048) keys[slot] = key;
        }
    }
    __syncthreads();
    int c0 = cnt;
    for (int i = tid; i < 2048; i += 256)
        if (i >= c0) keys[i] = 0ull;
    for (int k2 = 2; k2 <= 2048; k2 <<= 1)
        for (int j = k2 >> 1; j > 0; j >>= 1) {
            __syncthreads();
            for (int i = tid; i < 2048; i += 256) {
                int l = i ^ j;
                if (l > i) {
                    unsigned long long a = keys[i], c = keys[l];
                    bool up = (i & k2) == 0;
                    if (up ? (a < c) : (a > c)) { keys[i] = c; keys[l] = a; }
                }
            }
        }
    __syncthreads();
    const double* pr = propsD + (size_t)b * NSC * 4;
    double* bs = boxesD + (size_t)b * PRE_N * 4;
    for (int r = tid; r < PRE_N; r += 256) {
        int idx = (int)((~keys[r]) & 0x7FFF);
        if (idx >= NSC) idx = 0;
        bs[r * 4 + 0] = pr[(size_t)idx * 4 + 0];
        bs[r * 4 + 1] = pr[(size_t)idx * 4 + 1];
        bs[r * 4 + 2] = pr[(size_t)idx * 4 + 2];
        bs[r * 4 + 3] = pr[(size_t)idx * 4 + 3];
    }
}

// K4a: fp64 suppression bitmask. Interleaved: word w (0..31), bit t -> j = t*32 + w.
__global__ __launch_bounds__(256) void iou_mask_kernel(const double* __restrict__ boxesD,
                                                       unsigned long long* __restrict__ supmask) {
    __shared__ double bx[PRE_N * 4];
    int b = blockIdx.x;
    int i0 = blockIdx.y * 80;
    const double* src = boxesD + (size_t)b * PRE_N * 4;
    for (int o = threadIdx.x; o < PRE_N * 4; o += 256) bx[o] = src[o];
    __syncthreads();
    int ty = threadIdx.x >> 5, jw = threadIdx.x & 31;
    for (int ii = ty; ii < 80; ii += 8) {
        int i = i0 + ii;
        double bix1 = bx[i * 4 + 0], biy1 = bx[i * 4 + 1], bix2 = bx[i * 4 + 2], biy2 = bx[i * 4 + 3];
        double areai = (bix2 - bix1 + 1.0) * (biy2 - biy1 + 1.0);
        unsigned long long bits = 0ull;
        for (int t = 0; t < 64; ++t) {
            int j = t * 32 + jw;
            if (j > i && j < PRE_N) {
                double bjx1 = bx[j * 4 + 0], bjy1 = bx[j * 4 + 1], bjx2 = bx[j * 4 + 2], bjy2 = bx[j * 4 + 3];
                double iw = fmin(bix2, bjx2) - fmax(bix1, bjx1) + 1.0; iw = fmax(iw, 0.0);
                double ih = fmin(biy2, bjy2) - fmax(biy1, bjy1) + 1.0; ih = fmax(ih, 0.0);
                double inter = iw * ih;
                double areaj = (bjx2 - bjx1 + 1.0) * (bjy2 - bjy1 + 1.0);
                double iou = inter / (areai + areaj - inter);
                if (iou > 0.7) bits |= (1ull << t);
            }
        }
        supmask[((size_t)b * PRE_N + i) * 32 + jw] = bits;
    }
}

// K4b: sequential greedy suppression + first-300-kept (stable fill) + fp32 output
__global__ void nms_final_kernel(const unsigned long long* __restrict__ supmask,
                                 const double* __restrict__ boxesD,
                                 float* __restrict__ out) {
    int b = blockIdx.x;
    int lane = threadIdx.x;     // 64 threads
    int w = lane & 31;
    const unsigned long long* mask = supmask + (size_t)b * PRE_N * 32;
    int nbits = (w < 16) ? 63 : 62;
    unsigned long long kw = (1ull << nbits) - 1ull;
    unsigned long long rr[16];
#pragma unroll
    for (int d2 = 0; d2 < 16; ++d2) rr[d2] = mask[d2 * 32 + w];
    for (int i = 0; i < PRE_N; i += 16) {
#pragma unroll
        for (int u2 = 0; u2 < 16; ++u2) {
            int ii = i + u2;
            unsigned long long rcur = rr[u2];
            int ip = ii + 16;
            rr[u2] = (ip < PRE_N) ? mask[ip * 32 + w] : 0ull;
            unsigned long long kword = __shfl(kw, ii & 31);
            if ((kword >> (ii >> 5)) & 1ull) kw &= ~rcur;
        }
    }
    __shared__ unsigned long long keepw[32];
    __shared__ int pos[POST_N];
    if (lane < 32) keepw[lane] = kw;
    __syncthreads();
    if (lane == 0) {
        int c2 = 0;
        for (int j = 0; j < PRE_N && c2 < POST_N; ++j)
            if ((keepw[j & 31] >> (j >> 5)) & 1ull) pos[c2++] = j;
        for (int j = 0; j < PRE_N && c2 < POST_N; ++j)
            if (!((keepw[j & 31] >> (j >> 5)) & 1ull)) pos[c2++] = j;
    }
    __syncthreads();
    for (int r = lane; r < POST_N; r += 64) {
        int p = pos[r];
        const double* bxp = boxesD + ((size_t)b * PRE_N + p) * 4;
        float* o = out + ((size_t)b * POST_N + r) * 5;
        o[0] = (float)b; o[1] = (float)bxp[0]; o[2] = (float)bxp[1];
        o[3] = (float)bxp[2]; o[4] = (float)bxp[3];
    }
    if (b == 0 && lane == 0) { out[BATCH * POST_N * 5] = 0.f; out[BATCH * POST_N * 5 + 1] = 0.f; }
}

extern "C" void kernel_launch(void* const* d_in, const int* in_sizes, int n_in,
                              void* d_out, int out_size, void* d_ws, size_t ws_size,
                              hipStream_t stream) {
    (void)in_sizes; (void)n_in; (void)out_size; (void)ws_size;
    const float* base_feat = (const float*)d_in[0];
    const float* im_info   = (const float*)d_in[1];
    const float* W_conv    = (const float*)d_in[4];
    const float* b_conv    = (const float*)d_in[5];
    const float* W_cls     = (const float*)d_in[6];
    const float* b_cls     = (const float*)d_in[7];
    const float* W_bbox    = (const float*)d_in[8];
    const float* b_bbox    = (const float*)d_in[9];
    float* out = (float*)d_out;

    double* featD   = (double*)d_ws;            // 9,805,824 d
    double* out54D  = featD + 9805824;          // 1,225,728 d
    double* scoresD = out54D + 1225728;         //   172,368 d
    double* propsD  = scoresD + 172368;         //   689,472 d
    double* boxesD  = propsD + 689472;          //    64,000 d
    double* Wt2pD   = boxesD + 64000;           //    32,768 d
    unsigned long long* supmask = (unsigned long long*)(Wt2pD + 32768); // 512,000 u64
    float* Wt       = (float*)(supmask + 512000);                       // 4,718,592 f32
    // tab aliases propsD: probe writes it first; conv consumes it; propsD is
    // only written later by proposals_kernel — disjoint lifetimes.
    int* tab = (int*)propsD;                    // 768 ints

    mfma_probe_kernel<<<1, 64, 0, stream>>>(tab);
    wt3x3_kernel<<<(K_TOT * CMID + 255) / 256, 256, 0, stream>>>(W_conv, Wt);
    wt1x1_kernel<<<(CMID * 64 + 255) / 256, 256, 0, stream>>>(W_cls, W_bbox, Wt2pD);
    conv3x3_fused<<<dim3(7, 300), 256, 0, stream>>>(base_feat, Wt, b_conv, tab, featD);
    conv1x1_kernel<<<M_TOT / 4, 256, 0, stream>>>(featD, Wt2pD, b_cls, b_bbox, out54D);
    proposals_kernel<<<(BATCH * NSC + 255) / 256, 256, 0, stream>>>(out54D, im_info, scoresD, propsD);
    select_kernel<<<BATCH, 256, 0, stream>>>(scoresD, propsD, boxesD);
    iou_mask_kernel<<<dim3(BATCH, 25), 256, 0, stream>>>(boxesD, supmask);
    nms_final_kernel<<<BATCH, 64, 0, stream>>>(supmask, boxesD, out);
}

// Round 8
// 4222.536 us; speedup vs baseline: 1.2450x; 1.2450x over previous
//
#include <hip/hip_runtime.h>

#define FHH 38
#define FWW 63
#define NPIX 2394        // 38*63
#define BATCH 8
#define CIN 1024
#define CMID 512
#define NSC 21546        // NPIX*9
#define M_TOT 19152      // BATCH*NPIX
#define K_TOT 9216       // CIN*9
#define PRE_N 2000
#define POST_N 300
#define XSPLANE (8ll * NPIX * 1024)   // bytes per slice plane of xs

typedef double f64x4 __attribute__((ext_vector_type(4)));
typedef int    i32x4 __attribute__((ext_vector_type(4)));

// exact anchors
__device__ const double ANCX1[9] = {-84.,-176.,-360.,-56.,-120.,-248.,-36.,-80.,-168.};
__device__ const double ANCY1[9] = {-40.,-88.,-184.,-56.,-120.,-248.,-80.,-168.,-344.};
__device__ const double ANCX2[9] = {99.,191.,375.,71.,135.,263.,51.,95.,183.};
__device__ const double ANCY2[9] = {55.,103.,199.,71.,135.,263.,95.,183.,359.};

// ---------------------------------------------------------------------------
// f64 MFMA layout probe (unchanged, needed by the fallback f64 conv)
// ---------------------------------------------------------------------------
__global__ void mfma_probe_kernel(int* __restrict__ tab) {
    const int l = threadIdx.x;
    __shared__ int aiS[64], bjS[64], kbS[64];
    const f64x4 zero = {0.0, 0.0, 0.0, 0.0};
    int di[4] = {-1, -1, -1, -1}, dj[4] = {-1, -1, -1, -1};
    int ai_l = 0, bj_l = 0, ka_l = 0;
    kbS[l] = 0x7fffffff;
    __syncthreads();
    const double bval = __longlong_as_double((long long)(1023 + l) << 52);
    for (int p = 0; p < 64; ++p) {
        double a = (l == p) ? 1.0 : 0.0;
        f64x4 d = __builtin_amdgcn_mfma_f64_16x16x4f64(a, bval, zero, 0, 0, 0);
        int lmin = 0x7fffffff, kmin = 0x7fffffff;
        bool lit[4]; int qv[4];
#pragma unroll
        for (int r = 0; r < 4; ++r) {
            lit[r] = (d[r] != 0.0);
            qv[r] = ((__double2hiint(d[r]) >> 20) & 0x7ff) - 1023;
            if (lit[r]) { lmin = min(lmin, di[r] < 0 ? p : di[r]); kmin = min(kmin, qv[r]); }
        }
#pragma unroll
        for (int off = 32; off > 0; off >>= 1) {
            lmin = min(lmin, __shfl_xor(lmin, off));
            kmin = min(kmin, __shfl_xor(kmin, off));
        }
#pragma unroll
        for (int r = 0; r < 4; ++r)
            if (lit[r]) { di[r] = lmin; atomicMin(&kbS[qv[r]], kmin); }
        if (l == p) { ai_l = lmin; ka_l = kmin; }
    }
    for (int q = 0; q < 64; ++q) {
        double b = (l == q) ? 1.0 : 0.0;
        f64x4 d = __builtin_amdgcn_mfma_f64_16x16x4f64(1.0, b, zero, 0, 0, 0);
        int lmin = 0x7fffffff;
        bool lit[4];
#pragma unroll
        for (int r = 0; r < 4; ++r) {
            lit[r] = (d[r] != 0.0);
            if (lit[r]) lmin = min(lmin, dj[r] < 0 ? q : dj[r]);
        }
#pragma unroll
        for (int off = 32; off > 0; off >>= 1) lmin = min(lmin, __shfl_xor(lmin, off));
#pragma unroll
        for (int r = 0; r < 4; ++r) if (lit[r]) dj[r] = lmin;
        if (l == q) bj_l = lmin;
    }
    aiS[l] = ai_l; bjS[l] = bj_l;
    __syncthreads();
    int kb_l = kbS[l];
    int a_row_rk = 0, a_k_rk = 0, b_k_rk = 0, b_col_rk = 0;
    for (int t = 0; t < 64; ++t) {
        a_row_rk += (aiS[t] == t && t < ai_l);
        b_col_rk += (bjS[t] == t && t < bj_l);
        a_k_rk   += (kbS[t] == t && t < ka_l);
        b_k_rk   += (kbS[t] == t && t < kb_l);
    }
    tab[l] = a_row_rk; tab[64 + l] = a_k_rk; tab[128 + l] = b_k_rk; tab[192 + l] = b_col_rk;
#pragma unroll
    for (int r = 0; r < 4; ++r) {
        int dr = 0, dc = 0;
        for (int t = 0; t < 64; ++t) {
            dr += (aiS[t] == t && t < di[r]);
            dc += (bjS[t] == t && t < dj[r]);
        }
        tab[256 + l * 4 + r] = dr;
        tab[512 + l * 4 + r] = dc;
    }
}

// ---------------------------------------------------------------------------
// i8 path setup kernels
// ---------------------------------------------------------------------------
__global__ void flaginit_kernel(int* __restrict__ f) {
    if (threadIdx.x == 0) { f[0] = 0; f[1] = 0; f[2] = 0; f[3] = 0; f[4] = 0; }
}

// validate assumed v_mfma_i32_16x16x64_i8 layout:
//  A: row=l&15, k=(l>>4)*16+byte ; B: col=l&15, same k ; D: col=l&15, row=(l>>4)*4+reg
__global__ void validate_i8_kernel(int* __restrict__ flags) {
    const int l = threadIdx.x;
    signed char av[16], bv[16];
#pragma unroll
    for (int t = 0; t < 16; ++t) {
        int k = (l >> 4) * 16 + t;
        av[t] = (signed char)(((3 * (l & 15) + 5 * k) % 97) - 48);
        bv[t] = (signed char)(((7 * (l & 15) + 11 * k) % 93) - 46);
    }
    i32x4 a = *(i32x4*)av, b = *(i32x4*)bv;
    i32x4 d = {0, 0, 0, 0};
    asm("v_mfma_i32_16x16x64_i8 %0, %1, %2, %0" : "+v"(d) : "v"(a), "v"(b));
    bool ok = true;
#pragma unroll
    for (int r = 0; r < 4; ++r) {
        int row = (l >> 4) * 4 + r, col = l & 15;
        int ref = 0;
        for (int k = 0; k < 64; ++k)
            ref += (((3 * row + 5 * k) % 97) - 48) * (((7 * col + 11 * k) % 93) - 46);
        ok = ok && (d[r] == ref);
    }
    unsigned long long m = __ballot(ok);
    if (l == 0) flags[0] = (m == ~0ull) ? 1 : 0;
}

__global__ void maxabs_kernel(const float* __restrict__ p, long long n, unsigned* __restrict__ out) {
    unsigned mx = 0u;
    for (long long i = blockIdx.x * 256ll + threadIdx.x; i < n; i += (long long)gridDim.x * 256)
        mx = max(mx, __float_as_uint(p[i]) & 0x7fffffffu);
#pragma unroll
    for (int off = 32; off > 0; off >>= 1)
        mx = max(mx, (unsigned)__shfl_xor((int)mx, off));
    if ((threadIdx.x & 63) == 0) atomicMax(out, mx);
}

__global__ void prep_kernel(int* __restrict__ flags) {
    if (threadIdx.x == 0) {
        unsigned ax = (unsigned)flags[3], aw = (unsigned)flags[4];
        flags[1] = (int)((ax >> 23) & 255u) - 127 + 2;   // EA: |x|/2^EA <= 0.5
        flags[2] = (int)((aw >> 23) & 255u) - 127 + 2;   // EB
    }
}

// slice x -> xs[s][b][pix][ci] i8 (balanced base-128 digits), via LDS transpose
__global__ __launch_bounds__(256) void slice_x_kernel(
    const float* __restrict__ x, const int* __restrict__ flags,
    signed char* __restrict__ xs) {
    if (flags[0] != 1) return;
    const int EA = flags[1];
    __shared__ float T[64][65];
    int b = blockIdx.z, ci0 = blockIdx.y * 64, p0 = blockIdx.x * 64;
    int cj = threadIdx.x & 63, ri = threadIdx.x >> 6;
#pragma unroll
    for (int rr = 0; rr < 16; ++rr) {
        int row = ri * 16 + rr;
        int pix = p0 + cj;
        T[row][cj] = (pix < NPIX) ? x[((size_t)(b * CIN + ci0 + row)) * NPIX + pix] : 0.f;
    }
    __syncthreads();
#pragma unroll
    for (int rr = 0; rr < 16; ++rr) {
        int p = ri * 16 + rr;
        int pix = p0 + p;
        if (pix >= NPIX) continue;
        double u = ldexp((double)T[cj][p], -EA);
        size_t base = ((size_t)b * NPIX + pix) * 1024 + ci0 + cj;
#pragma unroll
        for (int s = 0; s < 6; ++s) {
            u *= 128.0; double d = rint(u); u -= d;
            xs[(size_t)s * XSPLANE + base] = (signed char)(int)d;
        }
    }
}

// slice W_conv -> ws8[s][co][k] i8, k = (kh*3+kw)*1024+ci
__global__ void slice_w_kernel(const float* __restrict__ W, const int* __restrict__ flags,
                               signed char* __restrict__ ws8) {
    if (flags[0] != 1) return;
    const int EB = flags[2];
    long long gid = blockIdx.x * 256ll + threadIdx.x;
    if (gid >= (long long)CMID * K_TOT) return;
    int co = (int)(gid / K_TOT);
    int k = (int)(gid - (long long)co * K_TOT);
    int pl = k >> 10, ci = k & 1023;
    double u = ldexp((double)W[((size_t)co * CIN + ci) * 9 + pl], -EB);
#pragma unroll
    for (int s = 0; s < 6; ++s) {
        u *= 128.0; double d = rint(u); u -= d;
        ws8[(size_t)s * (512ll * K_TOT) + (size_t)co * K_TOT + k] = (signed char)(int)d;
    }
}

// ---------------------------------------------------------------------------
// i8-Ozaki exact conv: 21 digit-pair GEMMs on v_mfma_i32_16x16x64_i8,
// s-grouped i32 accumulators (exact), fp64 combine. Block 128m x 64n, 8 waves
// (4m x 2n), wave 32x32 = 2x2 of 16x16 tiles. A via LDS (48KB), B direct from
// L2 (per-n-strip 3.5MB fits per-XCD L2; grid.x=8 => natural XCD pinning).
// ---------------------------------------------------------------------------
__global__ __launch_bounds__(512, 1) void conv3x3_i8(
    const signed char* __restrict__ xs, const signed char* __restrict__ ws8,
    const float* __restrict__ bconv, const int* __restrict__ flags,
    double* __restrict__ feat) {
    if (flags[0] != 1) return;
    const int EA = flags[1], EB = flags[2];
    __shared__ signed char Al[6 * 4 * 128 * 16];   // 48 KB  [s][g][m][16]
    const int tid = threadIdx.x;
    const int l = tid & 63, wid = tid >> 6;
    const int wm = wid >> 1, wn = wid & 1;
    const int n0 = blockIdx.x * 64;
    const int m0 = blockIdx.y * 128;

    // A staging identity: this thread stages (mloc, g) for slices 0..5
    const int mloc = (tid >> 2) & 127;
    const int g = tid & 3;
    const int m = m0 + mloc;
    const bool vm = (m < M_TOT);
    int b = 0, yy = 0, xx = 0;
    if (vm) { b = m / NPIX; int r = m - b * NPIX; yy = r / FWW; xx = r - yy * FWW; }

    i32x4 acc[6][2][2];
#pragma unroll
    for (int s = 0; s < 6; ++s)
#pragma unroll
        for (int rt = 0; rt < 2; ++rt)
#pragma unroll
            for (int ct = 0; ct < 2; ++ct) acc[s][rt][ct] = (i32x4){0, 0, 0, 0};

    const int bcol0 = n0 + wn * 32 + (l & 15);
    const int kgrp = (l >> 4) * 16;

    for (int kc = 0; kc < 144; ++kc) {
        const int pl = kc >> 4;
        const int kh = pl / 3, kw = pl - kh * 3;
        const int ci0 = (kc & 15) << 6;
        const int iy = yy + kh - 1, ix = xx + kw - 1;
        const bool ok = vm && iy >= 0 && iy < FHH && ix >= 0 && ix < FWW;
        i32x4 va[6];
        const size_t abase = ok ? ((size_t)(b * NPIX + iy * FWW + ix) * 1024 + ci0 + g * 16) : 0;
#pragma unroll
        for (int s = 0; s < 6; ++s) {
            i32x4 v = {0, 0, 0, 0};
            if (ok) v = *(const i32x4*)(xs + (size_t)s * XSPLANE + abase);
            va[s] = v;
        }
        __syncthreads();     // prior iteration's frag reads complete
#pragma unroll
        for (int s = 0; s < 6; ++s)
            *(i32x4*)&Al[(((s << 2) + g) << 11) + (mloc << 4)] = va[s];
        __syncthreads();
        i32x4 af[6][2];
#pragma unroll
        for (int s = 0; s < 6; ++s)
#pragma unroll
            for (int rt = 0; rt < 2; ++rt)
                af[s][rt] = *(const i32x4*)&Al[(((s << 2) + (l >> 4)) << 11)
                                               + ((wm * 32 + rt * 16 + (l & 15)) << 4)];
        const size_t kb = (size_t)pl * 1024 + ci0 + kgrp;
#pragma unroll
        for (int j = 0; j < 6; ++j) {
            i32x4 bf0 = *(const i32x4*)(ws8 + ((size_t)(j * 512 + bcol0) * K_TOT) + kb);
            i32x4 bf1 = *(const i32x4*)(ws8 + ((size_t)(j * 512 + bcol0 + 16) * K_TOT) + kb);
#pragma unroll
            for (int i = 0; i + j < 6; ++i) {
                asm("v_mfma_i32_16x16x64_i8 %0, %1, %2, %0" : "+v"(acc[i + j][0][0]) : "v"(af[i][0]), "v"(bf0));
                asm("v_mfma_i32_16x16x64_i8 %0, %1, %2, %0" : "+v"(acc[i + j][0][1]) : "v"(af[i][0]), "v"(bf1));
                asm("v_mfma_i32_16x16x64_i8 %0, %1, %2, %0" : "+v"(acc[i + j][1][0]) : "v"(af[i][1]), "v"(bf0));
                asm("v_mfma_i32_16x16x64_i8 %0, %1, %2, %0" : "+v"(acc[i + j][1][1]) : "v"(af[i][1]), "v"(bf1));
            }
        }
    }
    double sc[6];
#pragma unroll
    for (int s = 0; s < 6; ++s) sc[s] = ldexp(1.0, EA + EB - 7 * (s + 2));
#pragma unroll
    for (int rt = 0; rt < 2; ++rt)
#pragma unroll
        for (int ct = 0; ct < 2; ++ct)
#pragma unroll
            for (int r = 0; r < 4; ++r) {
                int grow = m0 + wm * 32 + rt * 16 + (l >> 4) * 4 + r;
                int gcol = n0 + wn * 32 + ct * 16 + (l & 15);
                if (grow < M_TOT) {
                    double v = (double)bconv[gcol];
#pragma unroll
                    for (int s = 0; s < 6; ++s) v += sc[s] * (double)acc[s][rt][ct][r];
                    feat[(size_t)grow * CMID + gcol] = fmax(v, 0.0);
                }
            }
}

// K0: W_conv -> Wt[k][co] fp32 (for f64 fallback)
__global__ void wt3x3_kernel(const float* __restrict__ W, float* __restrict__ Wt) {
    int gid = blockIdx.x * 256 + threadIdx.x;
    if (gid >= K_TOT * CMID) return;
    int co = gid & 511;
    int k  = gid >> 9;
    int pl = k >> 10;
    int ci = k & 1023;
    Wt[gid] = W[((size_t)co * CIN + ci) * 9 + pl];
}

__global__ void wt1x1_kernel(const float* __restrict__ Wc, const float* __restrict__ Wb,
                             double* __restrict__ Wt2pD) {
    int gid = blockIdx.x * 256 + threadIdx.x;
    if (gid >= CMID * 64) return;
    int n = gid & 63, k = gid >> 6;
    double v = 0.0;
    if (n < 18)      v = (double)Wc[(size_t)n * CMID + k];
    else if (n < 54) v = (double)Wb[(size_t)(n - 18) * CMID + k];
    Wt2pD[gid] = v;
}

// Fallback f64 MFMA conv (R6-verified), runs only when flags[0]==0
#define ASZ (32 * 72)
__global__ __launch_bounds__(256, 4) void conv3x3_mfma(
    const float* __restrict__ x, const float* __restrict__ Wt,
    const float* __restrict__ bconv, const int* __restrict__ tab,
    const int* __restrict__ flags, double* __restrict__ feat) {
    if (flags[0] == 1) return;
    __shared__ float As[2 * ASZ];
    __shared__ float Bs[2 * ASZ];
    const int tid = threadIdx.x;
    const int lane = tid & 63;
    const int wave = tid >> 6;
    const int wm = wave >> 1;
    const int wn = wave & 1;
    const int n0 = blockIdx.x * 64;
    const int m0 = blockIdx.y * 64;

    const int aRow = tab[lane];
    const int aK   = tab[64 + lane];
    const int bK   = tab[128 + lane];
    const int bCol = tab[192 + lane];
    int dRow[4], dCol[4];
#pragma unroll
    for (int r = 0; r < 4; ++r) {
        dRow[r] = tab[256 + lane * 4 + r];
        dCol[r] = tab[512 + lane * 4 + r];
    }
    const int mm = tid & 63;
    const int t6 = tid >> 6;
    const int m = m0 + mm;
    const bool vm = (m < M_TOT);
    int b = 0, yy = 0, xx = 0;
    if (vm) { b = m / NPIX; int r = m - b * NPIX; yy = r / FWW; xx = r - yy * FWW; }
    const int bk2 = tid >> 4;
    const int bn2 = (tid & 15) << 2;

    f64x4 acc[2][2];
#pragma unroll
    for (int i = 0; i < 2; ++i)
#pragma unroll
        for (int j = 0; j < 2; ++j) acc[i][j] = (f64x4){0.0, 0.0, 0.0, 0.0};

    const float* aBase = &As[aK * 72 + wm * 32 + aRow];
    const float* bBase = &Bs[bK * 72 + wn * 32 + bCol];

#define STAGE_REGS(KC, VA, VB0, VB1) do {                                     \
        const int pl_ = (KC) >> 5;                                            \
        const int kh_ = pl_ / 3, kw_ = pl_ - kh_ * 3;                         \
        const int ci0_ = ((KC) & 31) << 5;                                    \
        const int iy_ = yy + kh_ - 1, ix_ = xx + kw_ - 1;                     \
        const bool ok_ = vm && (iy_ >= 0) && (iy_ < FHH) && (ix_ >= 0) && (ix_ < FWW); \
        const float* ap_ = x + ((size_t)(b * CIN + ci0_ + t6)) * NPIX + iy_ * FWW + ix_; \
        _Pragma("unroll")                                                     \
        for (int r = 0; r < 8; ++r) {                                         \
            float v_ = 0.f;                                                   \
            if (ok_) v_ = ap_[(size_t)r * 4 * NPIX];                          \
            VA[r] = v_;                                                       \
        }                                                                     \
        const float4* wp_ = (const float4*)(Wt + (size_t)(((KC) << 5) + bk2) * CMID + n0 + bn2); \
        VB0 = wp_[0];                                                         \
        VB1 = wp_[2048];                                                      \
    } while (0)

#define WRITE_TILE(BUF, VA, VB0, VB1) do {                                    \
        _Pragma("unroll")                                                     \
        for (int r = 0; r < 8; ++r)                                           \
            As[(BUF) * ASZ + (t6 + r * 4) * 72 + mm] = VA[r];                 \
        *(float4*)&Bs[(BUF) * ASZ + bk2 * 72 + bn2] = VB0;                    \
        *(float4*)&Bs[(BUF) * ASZ + (bk2 + 16) * 72 + bn2] = VB1;             \
    } while (0)

#define MFMA_PHASE(BUF) do {                                                  \
        _Pragma("unroll")                                                     \
        for (int ks = 0; ks < 8; ++ks) {                                      \
            double a0 = (double)aBase[(BUF) * ASZ + ks * 288];                \
            double a1 = (double)aBase[(BUF) * ASZ + ks * 288 + 16];           \
            double b0 = (double)bBase[(BUF) * ASZ + ks * 288];                \
            double b1 = (double)bBase[(BUF) * ASZ + ks * 288 + 16];           \
            acc[0][0] = __builtin_amdgcn_mfma_f64_16x16x4f64(a0, b0, acc[0][0], 0, 0, 0); \
            acc[0][1] = __builtin_amdgcn_mfma_f64_16x16x4f64(a0, b1, acc[0][1], 0, 0, 0); \
            acc[1][0] = __builtin_amdgcn_mfma_f64_16x16x4f64(a1, b0, acc[1][0], 0, 0, 0); \
            acc[1][1] = __builtin_amdgcn_mfma_f64_16x16x4f64(a1, b1, acc[1][1], 0, 0, 0); \
        }                                                                     \
    } while (0)

    float va[8]; float4 vb0, vb1;
    float wa[8]; float4 wb0, wb1;
    STAGE_REGS(0, va, vb0, vb1);
    WRITE_TILE(0, va, vb0, vb1);
    __syncthreads();
    for (int kc = 0; kc < 288; kc += 2) {
        STAGE_REGS(kc + 1, wa, wb0, wb1);
        MFMA_PHASE(0);
        WRITE_TILE(1, wa, wb0, wb1);
        __syncthreads();
        if (kc + 2 < 288) {
            STAGE_REGS(kc + 2, va, vb0, vb1);
            MFMA_PHASE(1);
            WRITE_TILE(0, va, vb0, vb1);
            __syncthreads();
        } else {
            MFMA_PHASE(1);
        }
    }
#undef STAGE_REGS
#undef WRITE_TILE
#undef MFMA_PHASE
#pragma unroll
    for (int mi = 0; mi < 2; ++mi)
#pragma unroll
        for (int nj = 0; nj < 2; ++nj)
#pragma unroll
            for (int r = 0; r < 4; ++r) {
                int mg  = m0 + wm * 32 + mi * 16 + dRow[r];
                int col = n0 + wn * 32 + nj * 16 + dCol[r];
                if (mg < M_TOT)
                    feat[(size_t)mg * CMID + col] =
                        fmax(acc[mi][nj][r] + (double)bconv[col], 0.0);
            }
}

// K2: 1x1 convs, fp64
__global__ __launch_bounds__(256) void conv1x1_kernel(
    const double* __restrict__ feat, const double* __restrict__ Wt2pD,
    const float* __restrict__ bcls, const float* __restrict__ bbx,
    double* __restrict__ out54) {
    __shared__ double As[4 * 512];
    __shared__ double Bsh[64 * 64];
    int tid = threadIdx.x;
    int m0 = blockIdx.x * 4;
    for (int off = tid; off < 2048; off += 256) As[off] = feat[(size_t)m0 * CMID + off];
    int p = tid >> 6, n = tid & 63;
    double acc = 0.0;
    for (int c = 0; c < 8; ++c) {
        __syncthreads();
        for (int off = tid; off < 4096; off += 256) Bsh[off] = Wt2pD[c * 4096 + off];
        __syncthreads();
        const double* ap = &As[p * 512 + c * 64];
#pragma unroll 8
        for (int k2 = 0; k2 < 64; ++k2) acc = fma(ap[k2], Bsh[k2 * 64 + n], acc);
    }
    if (n < 54) {
        double bias = (double)((n < 18) ? bcls[n] : bbx[n - 18]);
        out54[(size_t)(m0 + p) * 64 + n] = acc + bias;
    }
}

// K2b: softmax-pair + bbox decode + clip, fp64
__global__ void proposals_kernel(const double* __restrict__ out54, const float* __restrict__ iminfo,
                                 double* __restrict__ scoresD, double* __restrict__ propsD) {
    int gid = blockIdx.x * 256 + threadIdx.x;
    if (gid >= BATCH * NSC) return;
    int b = gid / NSC;
    int rem = gid - b * NSC;
    int p = rem / 9;
    int a = rem - p * 9;
    int y = p / FWW, x = p - y * FWW;
    int m = b * NPIX + p;
    const double* row = out54 + (size_t)m * 64;
    double s0 = row[a], s1 = row[9 + a];
    double mx = fmax(s0, s1);
    double e0 = exp(s0 - mx), e1 = exp(s1 - mx);
    scoresD[gid] = e1 / (e0 + e1);
    double dx = row[18 + 4 * a], dy = row[19 + 4 * a], dw = row[20 + 4 * a], dh = row[21 + 4 * a];
    double ax1 = x * 16.0 + ANCX1[a], ay1 = y * 16.0 + ANCY1[a];
    double ax2 = x * 16.0 + ANCX2[a], ay2 = y * 16.0 + ANCY2[a];
    double w = ax2 - ax1 + 1.0, h = ay2 - ay1 + 1.0;
    double cx = ax1 + 0.5 * w, cy = ay1 + 0.5 * h;
    double px = dx * w + cx, py = dy * h + cy;
    double pw = exp(dw) * w, ph = exp(dh) * h;
    double imh = (double)iminfo[b * 3 + 0], imw = (double)iminfo[b * 3 + 1];
    double x1 = fmin(fmax(px - 0.5 * pw, 0.0), imw - 1.0);
    double y1 = fmin(fmax(py - 0.5 * ph, 0.0), imh - 1.0);
    double x2 = fmin(fmax(px + 0.5 * pw, 0.0), imw - 1.0);
    double y2 = fmin(fmax(py + 0.5 * ph, 0.0), imh - 1.0);
    double* o = propsD + (size_t)gid * 4;
    o[0] = x1; o[1] = y1; o[2] = x2; o[3] = y2;
}

// K3: exact top-2000 radix-select + bitonic
__global__ __launch_bounds__(256) void select_kernel(const double* __restrict__ scoresD,
                                                     const double* __restrict__ propsD,
                                                     double* __restrict__ boxesD) {
    __shared__ unsigned int hist4[4][256];
    __shared__ unsigned int histf[256];
    __shared__ unsigned long long keys[2048];
    __shared__ unsigned long long sh_thr;
    __shared__ int sh_need;
    __shared__ int cnt;
    const int b = blockIdx.x, tid = threadIdx.x;
    const int w4 = tid >> 6;
    const double* sc = scoresD + (size_t)b * NSC;

    unsigned long long prefix = 0ull;
    int need = PRE_N;
    for (int d = 7; d >= 0; --d) {
        for (int z = tid; z < 1024; z += 256) ((unsigned int*)hist4)[z] = 0u;
        __syncthreads();
        const int shift = d * 8;
        const unsigned long long maskAbove = (d == 7) ? 0ull : (~0ull << (shift + 8));
        for (int i = tid; i < NSC; i += 256) {
            unsigned long long sb = (unsigned long long)__double_as_longlong(sc[i]);
            unsigned long long key = (sb & ~0x7FFFull) | (unsigned long long)((~i) & 0x7FFF);
            if (((key ^ prefix) & maskAbove) == 0ull)
                atomicAdd(&hist4[w4][(unsigned int)(key >> shift) & 255u], 1u);
        }
        __syncthreads();
        histf[tid] = hist4[0][tid] + hist4[1][tid] + hist4[2][tid] + hist4[3][tid];
        __syncthreads();
        if (tid == 0) {
            int acc = 0, v = 255;
            for (; v > 0; --v) {
                int c = (int)histf[v];
                if (acc + c >= need) break;
                acc += c;
            }
            sh_thr = prefix | ((unsigned long long)(unsigned int)v << shift);
            sh_need = need - acc;
        }
        __syncthreads();
        prefix = sh_thr;
        need = sh_need;
        __syncthreads();
    }
    if (tid == 0) cnt = 0;
    __syncthreads();
    for (int i = tid; i < NSC; i += 256) {
        unsigned long long sb = (unsigned long long)__double_as_longlong(sc[i]);
        unsigned long long key = (sb & ~0x7FFFull) | (unsigned long long)((~i) & 0x7FFF);
        if (key >= prefix) {
            int slot = atomicAdd(&cnt, 1);
            if (slot < 2048) keys[slot] = key;
        }
    }
    __syncthreads();
    int c0 = cnt;
    for (int i = tid; i < 2048; i += 256)
        if (i >= c0) keys[i] = 0ull;
    for (int k2 = 2; k2 <= 2048; k2 <<= 1)
        for (int j = k2 >> 1; j > 0; j >>= 1) {
            __syncthreads();
            for (int i = tid; i < 2048; i += 256) {
                int l = i ^ j;
                if (l > i) {
                    unsigned long long a = keys[i], c = keys[l];
                    bool up = (i & k2) == 0;
                    if (up ? (a < c) : (a > c)) { keys[i] = c; keys[l] = a; }
                }
            }
        }
    __syncthreads();
    const double* pr = propsD + (size_t)b * NSC * 4;
    double* bs = boxesD + (size_t)b * PRE_N * 4;
    for (int r = tid; r < PRE_N; r += 256) {
        int idx = (int)((~keys[r]) & 0x7FFF);
        if (idx >= NSC) idx = 0;
        bs[r * 4 + 0] = pr[(size_t)idx * 4 + 0];
        bs[r * 4 + 1] = pr[(size_t)idx * 4 + 1];
        bs[r * 4 + 2] = pr[(size_t)idx * 4 + 2];
        bs[r * 4 + 3] = pr[(size_t)idx * 4 + 3];
    }
}

// K4a: fp64 IoU suppression bitmask
__global__ __launch_bounds__(256) void iou_mask_kernel(const double* __restrict__ boxesD,
                                                       unsigned long long* __restrict__ supmask) {
    __shared__ double bx[PRE_N * 4];
    int b = blockIdx.x;
    int i0 = blockIdx.y * 80;
    const double* src = boxesD + (size_t)b * PRE_N * 4;
    for (int o = threadIdx.x; o < PRE_N * 4; o += 256) bx[o] = src[o];
    __syncthreads();
    int ty = threadIdx.x >> 5, jw = threadIdx.x & 31;
    for (int ii = ty; ii < 80; ii += 8) {
        int i = i0 + ii;
        double bix1 = bx[i * 4 + 0], biy1 = bx[i * 4 + 1], bix2 = bx[i * 4 + 2], biy2 = bx[i * 4 + 3];
        double areai = (bix2 - bix1 + 1.0) * (biy2 - biy1 + 1.0);
        unsigned long long bits = 0ull;
        for (int t = 0; t < 64; ++t) {
            int j = t * 32 + jw;
            if (j > i && j < PRE_N) {
                double bjx1 = bx[j * 4 + 0], bjy1 = bx[j * 4 + 1], bjx2 = bx[j * 4 + 2], bjy2 = bx[j * 4 + 3];
                double iw = fmin(bix2, bjx2) - fmax(bix1, bjx1) + 1.0; iw = fmax(iw, 0.0);
                double ih = fmin(biy2, bjy2) - fmax(biy1, bjy1) + 1.0; ih = fmax(ih, 0.0);
                double inter = iw * ih;
                double areaj = (bjx2 - bjx1 + 1.0) * (bjy2 - bjy1 + 1.0);
                double iou = inter / (areai + areaj - inter);
                if (iou > 0.7) bits |= (1ull << t);
            }
        }
        supmask[((size_t)b * PRE_N + i) * 32 + jw] = bits;
    }
}

// K4b: greedy suppression + first-300 + fp32 output
__global__ void nms_final_kernel(const unsigned long long* __restrict__ supmask,
                                 const double* __restrict__ boxesD,
                                 float* __restrict__ out) {
    int b = blockIdx.x;
    int lane = threadIdx.x;
    int w = lane & 31;
    const unsigned long long* mask = supmask + (size_t)b * PRE_N * 32;
    int nbits = (w < 16) ? 63 : 62;
    unsigned long long kw = (1ull << nbits) - 1ull;
    unsigned long long rr[16];
#pragma unroll
    for (int d2 = 0; d2 < 16; ++d2) rr[d2] = mask[d2 * 32 + w];
    for (int i = 0; i < PRE_N; i += 16) {
#pragma unroll
        for (int u2 = 0; u2 < 16; ++u2) {
            int ii = i + u2;
            unsigned long long rcur = rr[u2];
            int ip = ii + 16;
            rr[u2] = (ip < PRE_N) ? mask[ip * 32 + w] : 0ull;
            unsigned long long kword = __shfl(kw, ii & 31);
            if ((kword >> (ii >> 5)) & 1ull) kw &= ~rcur;
        }
    }
    __shared__ unsigned long long keepw[32];
    __shared__ int pos[POST_N];
    if (lane < 32) keepw[lane] = kw;
    __syncthreads();
    if (lane == 0) {
        int c2 = 0;
        for (int j = 0; j < PRE_N && c2 < POST_N; ++j)
            if ((keepw[j & 31] >> (j >> 5)) & 1ull) pos[c2++] = j;
        for (int j = 0; j < PRE_N && c2 < POST_N; ++j)
            if (!((keepw[j & 31] >> (j >> 5)) & 1ull)) pos[c2++] = j;
    }
    __syncthreads();
    for (int r = lane; r < POST_N; r += 64) {
        int p = pos[r];
        const double* bxp = boxesD + ((size_t)b * PRE_N + p) * 4;
        float* o = out + ((size_t)b * POST_N + r) * 5;
        o[0] = (float)b; o[1] = (float)bxp[0]; o[2] = (float)bxp[1];
        o[3] = (float)bxp[2]; o[4] = (float)bxp[3];
    }
    if (b == 0 && lane == 0) { out[BATCH * POST_N * 5] = 0.f; out[BATCH * POST_N * 5 + 1] = 0.f; }
}

extern "C" void kernel_launch(void* const* d_in, const int* in_sizes, int n_in,
                              void* d_out, int out_size, void* d_ws, size_t ws_size,
                              hipStream_t stream) {
    (void)in_sizes; (void)n_in; (void)out_size;
    const float* base_feat = (const float*)d_in[0];
    const float* im_info   = (const float*)d_in[1];
    const float* W_conv    = (const float*)d_in[4];
    const float* b_conv    = (const float*)d_in[5];
    const float* W_cls     = (const float*)d_in[6];
    const float* b_cls     = (const float*)d_in[7];
    const float* W_bbox    = (const float*)d_in[8];
    const float* b_bbox    = (const float*)d_in[9];
    float* out = (float*)d_out;

    double* featD   = (double*)d_ws;            // 9,805,824 d
    double* out54D  = featD + 9805824;          // 1,225,728 d
    double* scoresD = out54D + 1225728;         //   172,368 d
    double* propsD  = scoresD + 172368;         //   689,472 d
    double* boxesD  = propsD + 689472;          //    64,000 d
    double* Wt2pD   = boxesD + 64000;           //    32,768 d
    unsigned long long* supmask = (unsigned long long*)(Wt2pD + 32768); // 512,000 u64
    int* iflags     = (int*)(supmask + 512000);                         // 16 ints
    float* Wt       = (float*)(iflags + 16);                            // 4,718,592 f
    signed char* xs  = (signed char*)(Wt + 4718592);                    // 117,669,888 B
    signed char* ws8 = xs + (size_t)6 * XSPLANE;                        // 28,311,552 B
    int* tab = (int*)propsD;                    // 768 ints (aliased; disjoint lifetime)

    size_t need = (size_t)((char*)(ws8 + 6ll * 512 * K_TOT) - (char*)d_ws);
    bool i8cap = (ws_size >= need);

    flaginit_kernel<<<1, 64, 0, stream>>>(iflags);
    mfma_probe_kernel<<<1, 64, 0, stream>>>(tab);
    if (i8cap) {
        validate_i8_kernel<<<1, 64, 0, stream>>>(iflags);
        maxabs_kernel<<<1024, 256, 0, stream>>>(base_feat, (long long)BATCH * CIN * NPIX,
                                                (unsigned*)&iflags[3]);
        maxabs_kernel<<<128, 256, 0, stream>>>(W_conv, (long long)CMID * CIN * 9,
                                               (unsigned*)&iflags[4]);
        prep_kernel<<<1, 64, 0, stream>>>(iflags);
    }
    wt3x3_kernel<<<(K_TOT * CMID + 255) / 256, 256, 0, stream>>>(W_conv, Wt);
    wt1x1_kernel<<<(CMID * 64 + 255) / 256, 256, 0, stream>>>(W_cls, W_bbox, Wt2pD);
    if (i8cap) {
        slice_x_kernel<<<dim3(38, 16, 8), 256, 0, stream>>>(base_feat, iflags, xs);
        slice_w_kernel<<<(int)((4718592 + 255) / 256), 256, 0, stream>>>(W_conv, iflags, ws8);
        conv3x3_i8<<<dim3(8, 150), 512, 0, stream>>>(xs, ws8, b_conv, iflags, featD);
    }
    conv3x3_mfma<<<dim3(8, 300), 256, 0, stream>>>(base_feat, Wt, b_conv, tab, iflags, featD);
    conv1x1_kernel<<<M_TOT / 4, 256, 0, stream>>>(featD, Wt2pD, b_cls, b_bbox, out54D);
    proposals_kernel<<<(BATCH * NSC + 255) / 256, 256, 0, stream>>>(out54D, im_info, scoresD, propsD);
    select_kernel<<<BATCH, 256, 0, stream>>>(scoresD, propsD, boxesD);
    iou_mask_kernel<<<dim3(BATCH, 25), 256, 0, stream>>>(boxesD, supmask);
    nms_final_kernel<<<BATCH, 64, 0, stream>>>(supmask, boxesD, out);
}